// Round 9
// baseline (253.846 us; speedup 1.0000x reference)
//
#include <hip/hip_runtime.h>
#include <math.h>

#define L_SEQ   16384
#define DMODEL  1024
#define NST     512             // complex states
#define CHUNK   128
#define NCHUNK  (L_SEQ / CHUNK) // 128

typedef float  f32x4 __attribute__((ext_vector_type(4)));
typedef short  s16x8 __attribute__((ext_vector_type(8)));

__device__ __forceinline__ unsigned short f2bf(float f) {      // RNE
    union { float f; unsigned int u; } v; v.f = f;
    unsigned int r = v.u + 0x7fffu + ((v.u >> 16) & 1u);
    return (unsigned short)(r >> 16);
}
__device__ __forceinline__ unsigned short f2bf_fast(float f) { // round-half-up
    union { float f; unsigned int u; } v; v.f = f;
    return (unsigned short)((v.u + 0x8000u) >> 16);
}
__device__ __forceinline__ float bf2f(unsigned int h16) {
    union { unsigned int u; float f; } v; v.u = h16 << 16; return v.f;
}
__device__ __forceinline__ void mfma16(f32x4& d, s16x8 a, s16x8 b) {
    asm volatile("v_mfma_f32_16x16x32_bf16 %0, %1, %2, %0"
                 : "+v"(d) : "v"(a), "v"(b));
}
__device__ __forceinline__ uint4 pack8(float4 x, float4 y) {
    union { unsigned short u[8]; uint4 v; } t;
    t.u[0] = f2bf_fast(x.x); t.u[1] = f2bf_fast(x.y);
    t.u[2] = f2bf_fast(x.z); t.u[3] = f2bf_fast(x.w);
    t.u[4] = f2bf_fast(y.x); t.u[5] = f2bf_fast(y.y);
    t.u[6] = f2bf_fast(y.z); t.u[7] = f2bf_fast(y.w);
    return t.v;
}
// async global -> LDS, 16 bytes per lane (lane-linear LDS dest)
__device__ __forceinline__ void gload16(const unsigned short* g, unsigned short* l) {
    __builtin_amdgcn_global_load_lds(
        (const __attribute__((address_space(1))) unsigned int*)g,
        (__attribute__((address_space(3))) unsigned int*)l,
        16, 0, 0);
}

// ---------------- setup: lambda, lambda^128, gamma ----------------
__global__ void setup_params(const float* __restrict__ nu_log,
                             const float* __restrict__ theta_log,
                             const float* __restrict__ gamma_log,
                             float* __restrict__ lam,    // [2][512]
                             float* __restrict__ lamT,   // lambda^128
                             float* __restrict__ gam) {
    int s = threadIdx.x;
    if (s >= NST) return;
    float mod = expf(-expf(nu_log[s]));
    float th  = expf(theta_log[s]);
    float ar = mod * cosf(th);
    float ai = mod * sinf(th);
    lam[s] = ar; lam[NST + s] = ai;
    gam[s] = expf(gamma_log[s]);
    float pr = 1.f, pi = 0.f;
    for (int i = 0; i < CHUNK; ++i) {
        float nr = pr * ar - pi * ai;
        float ni = pr * ai + pi * ar;
        pr = nr; pi = ni;
    }
    lamT[s] = pr; lamT[NST + s] = pi;
}

// W1 row 2s = Bre[s,:], row 2s+1 = Bim[s,:]  (no gamma; applied fp32 in scan)
__global__ void pack_w1(const float* __restrict__ Bre, const float* __restrict__ Bim,
                        unsigned short* __restrict__ W1) {
    int idx = blockIdx.x * 256 + threadIdx.x;
    int n = idx >> 10, k = idx & 1023;
    int s = n >> 1;
    float v = (n & 1) ? Bim[s * DMODEL + k] : Bre[s * DMODEL + k];
    W1[idx] = f2bf(v);
}
// W2[n][2s] = Cre[n][s], W2[n][2s+1] = -Cim[n][s]
__global__ void pack_w2(const float* __restrict__ Cre, const float* __restrict__ Cim,
                        unsigned short* __restrict__ W2) {
    int idx = blockIdx.x * 256 + threadIdx.x;
    int n = idx >> 10, k = idx & 1023;
    int s = k >> 1;
    float v = (k & 1) ? -Cim[n * NST + s] : Cre[n * NST + s];
    W2[idx] = f2bf(v);
}

// ---------------- X fp32 -> bf16 (8 elems/thread) ----------------
__global__ __launch_bounds__(256)
void conv_x(const float4* __restrict__ X, uint4* __restrict__ Xb) {
    int i = blockIdx.x * 256 + threadIdx.x;
    float4 a = X[2 * i], b = X[2 * i + 1];
    Xb[i] = pack8(a, b);
}

// ======= bf16 MFMA GEMM: 128x128 tile, 2-phase, gload_lds, k-split LDS =======
// LDS regions As[g4][row128][8elem] (region g4 holds k = g4*8..g4*8+7):
// conflict-free ds_read_b128 under 32-lane halves (r7/8-validated), and the
// gload_lds dest stays exactly wave-base + lane*16.
// Epilogue: C-tile staged through LDS -> 64B/thread contiguous global stores.
// EPI=0: bf16 out; EPI=1: fp32 out + D*x (applied after the linear re-read).
template<int EPI>
__global__ __launch_bounds__(256)
void gemm_bf16(const unsigned short* __restrict__ A, const unsigned short* __restrict__ B,
               void* __restrict__ out, const float* __restrict__ Dv,
               const float* __restrict__ Xf) {
    const int K = 1024, N = 1024;
    __shared__ __align__(16) unsigned short sm[8192];   // 16 KiB
    unsigned short* As = sm;          // [4][128][8]
    unsigned short* Bs = sm + 4096;

    const int tid  = threadIdx.x;
    const int lane = tid & 63;
    const int wave = tid >> 6;
    const int wr   = wave >> 1, wc = wave & 1;

    // XCD-aware swizzle (nwg = 1024, %8 == 0 -> bijective)
    const int lin   = blockIdx.y * gridDim.x + blockIdx.x;
    const int n_new = (lin & 7) * 128 + (lin >> 3);
    const int bx = n_new & 7, by = n_new >> 3;
    const int m0 = by * 128, n0 = bx * 128;

    // staging source: dest short idx tid*8 -> region g4 = tid>>7, row = tid&127
    const int arow  = tid & 127;
    const int ahalf = tid >> 7;         // 0/1
    const unsigned short* Asrc = A + (size_t)(m0 + arow) * K + ahalf * 8;
    const unsigned short* Bsrc = B + (size_t)(n0 + arow) * K + ahalf * 8;

    f32x4 acc[4][4] = {};
    const int fr = lane & 15;
    const int g4 = lane >> 4;

    for (int k0 = 0; k0 < K; k0 += 32) {
        __syncthreads();                  // prev tile's ds_reads done
        gload16(Asrc + k0,      &As[tid * 8]);         // regions 0,1 (k 0..15)
        gload16(Asrc + k0 + 16, &As[2048 + tid * 8]);  // regions 2,3 (k 16..31)
        gload16(Bsrc + k0,      &Bs[tid * 8]);
        gload16(Bsrc + k0 + 16, &Bs[2048 + tid * 8]);
        __syncthreads();                  // vmcnt drained -> LDS ready

        s16x8 af[4], bfq[4];
        #pragma unroll
        for (int i = 0; i < 4; ++i)
            af[i] = *(const s16x8*)&As[g4 * 1024 + (wr * 64 + i * 16 + fr) * 8];
        #pragma unroll
        for (int j = 0; j < 4; ++j)
            bfq[j] = *(const s16x8*)&Bs[g4 * 1024 + (wc * 64 + j * 16 + fr) * 8];
        #pragma unroll
        for (int i = 0; i < 4; ++i)
            #pragma unroll
            for (int j = 0; j < 4; ++j)
                mfma16(acc[i][j], af[i], bfq[j]);
    }

    // ---- epilogue through LDS ----
    const int crow = g4 * 4;              // C/D: col=lane&15, row=g4*4+r
    const int ccol = fr;

    if (EPI == 0) {
        // 2 passes of 64 rows, bf16 [64][128] = 16KB
        #pragma unroll
        for (int p = 0; p < 2; ++p) {
            __syncthreads();
            if (wr == p) {
                #pragma unroll
                for (int i = 0; i < 4; ++i)
                    #pragma unroll
                    for (int j = 0; j < 4; ++j)
                        #pragma unroll
                        for (int r = 0; r < 4; ++r)
                            sm[(i * 16 + crow + r) * 128 + wc * 64 + j * 16 + ccol]
                                = f2bf(acc[i][j][r]);
            }
            __syncthreads();
            const int row = tid >> 2, cq = (tid & 3) * 32;
            const uint4* src = (const uint4*)&sm[row * 128 + cq];
            uint4 v0 = src[0], v1 = src[1], v2 = src[2], v3 = src[3];
            uint4* dst = (uint4*)&((unsigned short*)out)[(size_t)(m0 + p * 64 + row) * N + n0 + cq];
            dst[0] = v0; dst[1] = v1; dst[2] = v2; dst[3] = v3;
        }
    } else {
        // 4 passes of 32 rows, fp32 [32][128] = 16KB; D*x fused on re-read
        float* smf = (float*)sm;
        #pragma unroll
        for (int p = 0; p < 4; ++p) {
            __syncthreads();
            if (wr == (p >> 1)) {
                const int ib = (p & 1) * 2;
                #pragma unroll
                for (int ii = 0; ii < 2; ++ii)
                    #pragma unroll
                    for (int j = 0; j < 4; ++j)
                        #pragma unroll
                        for (int r = 0; r < 4; ++r)
                            smf[(ii * 16 + crow + r) * 128 + wc * 64 + j * 16 + ccol]
                                = acc[ib + ii][j][r];
            }
            __syncthreads();
            const int row = tid >> 3;          // 0..31
            const int cf  = (tid & 7) * 16;    // 16 floats = 64B
            const int m   = m0 + p * 32 + row;
            const float4* sp = (const float4*)&smf[row * 128 + cf];
            const float4* xp = (const float4*)&Xf[(size_t)m * N + n0 + cf];
            const float4* dp = (const float4*)&Dv[n0 + cf];
            float4*       yp = (float4*)&((float*)out)[(size_t)m * N + n0 + cf];
            #pragma unroll
            for (int q = 0; q < 4; ++q) {
                float4 v = sp[q], xv = xp[q], dv = dp[q], o;
                o.x = fmaf(dv.x, xv.x, v.x);
                o.y = fmaf(dv.y, xv.y, v.y);
                o.z = fmaf(dv.z, xv.z, v.z);
                o.w = fmaf(dv.w, xv.w, v.w);
                yp[q] = o;
            }
        }
    }
}

// ---------- scan pass 1: chunk ends only ----------
__global__ __launch_bounds__(128)
void scan_ends(const unsigned int* __restrict__ Bu, const float* __restrict__ lam,
               const float* __restrict__ gam, float* __restrict__ ends) {
    const int s = blockIdx.y * 128 + threadIdx.x;
    const int c = blockIdx.x;
    const float lr = lam[s], li = lam[NST + s], g = gam[s];
    float hr = 0.f, hi = 0.f;
    size_t base = (size_t)c * CHUNK * NST + s;
    #pragma unroll 4
    for (int t = 0; t < CHUNK; ++t) {
        unsigned int v = Bu[base + (size_t)t * NST];
        float br = g * bf2f(v & 0xffffu);
        float bi = g * bf2f(v >> 16);
        float nr = fmaf(lr, hr, fmaf(-li, hi, br));
        float ni = fmaf(lr, hi, fmaf( li, hr, bi));
        hr = nr; hi = ni;
    }
    ends[(size_t)(c * NST + s) * 2]     = hr;
    ends[(size_t)(c * NST + s) * 2 + 1] = hi;
}

// ---------- carry scan across chunks (16-deep static prefetch) ----------
__global__ __launch_bounds__(NST)
void scan_carry(const float* __restrict__ ends, const float* __restrict__ lamT,
                float* __restrict__ car) {
    const int s = threadIdx.x;
    const float ar = lamT[s], ai = lamT[NST + s];
    const float2* E = (const float2*)ends;   // index c*NST + s
    float2*       C = (float2*)car;
    float2 bufA[8], bufB[8];
    #pragma unroll
    for (int k = 0; k < 8; ++k) bufA[k] = E[(size_t)k * NST + s];
    float cr = 0.f, ci = 0.f;
    for (int cc = 0; cc < NCHUNK; cc += 16) {
        #pragma unroll
        for (int k = 0; k < 8; ++k)
            bufB[k] = E[(size_t)(cc + 8 + k) * NST + s];
        #pragma unroll
        for (int k = 0; k < 8; ++k) {
            float2 o; o.x = cr; o.y = ci;
            C[(size_t)(cc + k) * NST + s] = o;
            float nr = fmaf(ar, cr, fmaf(-ai, ci, bufA[k].x));
            float ni = fmaf(ar, ci, fmaf( ai, cr, bufA[k].y));
            cr = nr; ci = ni;
        }
        if (cc + 16 < NCHUNK) {
            #pragma unroll
            for (int k = 0; k < 8; ++k)
                bufA[k] = E[(size_t)(cc + 16 + k) * NST + s];
        }
        #pragma unroll
        for (int k = 0; k < 8; ++k) {
            float2 o; o.x = cr; o.y = ci;
            C[(size_t)(cc + 8 + k) * NST + s] = o;
            float nr = fmaf(ar, cr, fmaf(-ai, ci, bufB[k].x));
            float ni = fmaf(ar, ci, fmaf( ai, cr, bufB[k].y));
            cr = nr; ci = ni;
        }
    }
}

// ---------- scan pass 2: full scan from carry, write H bf16 (to Xb region) ----
__global__ __launch_bounds__(128)
void scan_h(const unsigned int* __restrict__ Bu, unsigned int* __restrict__ H,
            const float* __restrict__ lam, const float* __restrict__ gam,
            const float* __restrict__ car) {
    const int s = blockIdx.y * 128 + threadIdx.x;
    const int c = blockIdx.x;
    const float lr = lam[s], li = lam[NST + s], g = gam[s];
    float hr = car[(size_t)(c * NST + s) * 2];
    float hi = car[(size_t)(c * NST + s) * 2 + 1];
    size_t base = (size_t)c * CHUNK * NST + s;
    #pragma unroll 4
    for (int t = 0; t < CHUNK; ++t) {
        unsigned int v = Bu[base + (size_t)t * NST];
        float br = g * bf2f(v & 0xffffu);
        float bi = g * bf2f(v >> 16);
        float nr = fmaf(lr, hr, fmaf(-li, hi, br));
        float ni = fmaf(lr, hi, fmaf( li, hr, bi));
        hr = nr; hi = ni;
        H[base + (size_t)t * NST] =
            (unsigned int)f2bf(hr) | ((unsigned int)f2bf(hi) << 16);
    }
}

extern "C" void kernel_launch(void* const* d_in, const int* in_sizes, int n_in,
                              void* d_out, int out_size, void* d_ws, size_t ws_size,
                              hipStream_t stream) {
    const float* X         = (const float*)d_in[0];
    const float* nu_log    = (const float*)d_in[1];
    const float* theta_log = (const float*)d_in[2];
    const float* gamma_log = (const float*)d_in[3];
    const float* Bre       = (const float*)d_in[4];
    const float* Bim       = (const float*)d_in[5];
    const float* Cre       = (const float*)d_in[6];
    const float* Cim       = (const float*)d_in[7];
    const float* Dv        = (const float*)d_in[8];
    float* Y = (float*)d_out;

    // ws (~37 MB): Xb (later reused as H), W1, W2, small tables.
    // Bu (bf16 pairs, 32 MB) lives in d_out's first 32 MB; dead before gemm2 writes Y.
    char* ws = (char*)d_ws;
    size_t off = 0;
    unsigned short* Xb  = (unsigned short*)(ws + off); off += (size_t)L_SEQ * DMODEL * 2;  // 32MB
    unsigned short* H   = Xb;   // reuse: Xb dead after gemm1
    unsigned short* W1  = (unsigned short*)(ws + off); off += (size_t)DMODEL * DMODEL * 2; // 2MB
    unsigned short* W2  = (unsigned short*)(ws + off); off += (size_t)DMODEL * DMODEL * 2; // 2MB
    float* lam  = (float*)(ws + off); off += 1024 * 4;
    float* lamT = (float*)(ws + off); off += 1024 * 4;
    float* gam  = (float*)(ws + off); off += 512 * 4;
    float* ends = (float*)(ws + off); off += (size_t)NCHUNK * NST * 2 * 4;  // 512KB
    float* car  = (float*)(ws + off); off += (size_t)NCHUNK * NST * 2 * 4;  // 512KB
    unsigned short* Bu = (unsigned short*)d_out;

    setup_params<<<1, NST, 0, stream>>>(nu_log, theta_log, gamma_log, lam, lamT, gam);
    pack_w1<<<(DMODEL * DMODEL) / 256, 256, 0, stream>>>(Bre, Bim, W1);
    pack_w2<<<(DMODEL * DMODEL) / 256, 256, 0, stream>>>(Cre, Cim, W2);
    conv_x<<<(L_SEQ * DMODEL / 8) / 256, 256, 0, stream>>>((const float4*)X, (uint4*)Xb);

    dim3 gg(8, 128);
    gemm_bf16<0><<<gg, 256, 0, stream>>>(Xb, W1, Bu, nullptr, nullptr);

    dim3 gs(NCHUNK, 4);   // 128 chunks x 4 state-groups of 128
    scan_ends<<<gs, 128, 0, stream>>>((const unsigned int*)Bu, lam, gam, ends);
    scan_carry<<<1, NST, 0, stream>>>(ends, lamT, car);
    scan_h<<<gs, 128, 0, stream>>>((const unsigned int*)Bu, (unsigned int*)H, lam, gam, car);

    gemm_bf16<1><<<gg, 256, 0, stream>>>(H, W2, Y, Dv, X);
}

// Round 10
// 164.393 us; speedup vs baseline: 1.5441x; 1.5441x over previous
//
#include <hip/hip_runtime.h>
#include <math.h>

#define L_SEQ   16384
#define DMODEL  1024
#define NST     512             // complex states
#define CHUNK   128
#define NCHUNK  (L_SEQ / CHUNK) // 128

typedef float  f32x4 __attribute__((ext_vector_type(4)));
typedef short  s16x8 __attribute__((ext_vector_type(8)));

__device__ __forceinline__ unsigned short f2bf(float f) {      // RNE
    union { float f; unsigned int u; } v; v.f = f;
    unsigned int r = v.u + 0x7fffu + ((v.u >> 16) & 1u);
    return (unsigned short)(r >> 16);
}
__device__ __forceinline__ unsigned short f2bf_fast(float f) { // round-half-up
    union { float f; unsigned int u; } v; v.f = f;
    return (unsigned short)((v.u + 0x8000u) >> 16);
}
__device__ __forceinline__ float bf2f(unsigned int h16) {
    union { unsigned int u; float f; } v; v.u = h16 << 16; return v.f;
}
__device__ __forceinline__ void mfma16(f32x4& d, s16x8 a, s16x8 b) {
    asm volatile("v_mfma_f32_16x16x32_bf16 %0, %1, %2, %0"
                 : "+v"(d) : "v"(a), "v"(b));
}
__device__ __forceinline__ uint4 pack8(float4 x, float4 y) {
    union { unsigned short u[8]; uint4 v; } t;
    t.u[0] = f2bf_fast(x.x); t.u[1] = f2bf_fast(x.y);
    t.u[2] = f2bf_fast(x.z); t.u[3] = f2bf_fast(x.w);
    t.u[4] = f2bf_fast(y.x); t.u[5] = f2bf_fast(y.y);
    t.u[6] = f2bf_fast(y.z); t.u[7] = f2bf_fast(y.w);
    return t.v;
}
// async global -> LDS, 16 bytes per lane (lane-linear LDS dest)
__device__ __forceinline__ void gload16(const unsigned short* g, unsigned short* l) {
    __builtin_amdgcn_global_load_lds(
        (const __attribute__((address_space(1))) unsigned int*)g,
        (__attribute__((address_space(3))) unsigned int*)l,
        16, 0, 0);
}

// ---------------- setup: lambda, lambda^128, gamma ----------------
__global__ void setup_params(const float* __restrict__ nu_log,
                             const float* __restrict__ theta_log,
                             const float* __restrict__ gamma_log,
                             float* __restrict__ lam,    // [2][512]
                             float* __restrict__ lamT,   // lambda^128
                             float* __restrict__ gam) {
    int s = threadIdx.x;
    if (s >= NST) return;
    float mod = expf(-expf(nu_log[s]));
    float th  = expf(theta_log[s]);
    float ar = mod * cosf(th);
    float ai = mod * sinf(th);
    lam[s] = ar; lam[NST + s] = ai;
    gam[s] = expf(gamma_log[s]);
    float pr = 1.f, pi = 0.f;
    for (int i = 0; i < CHUNK; ++i) {
        float nr = pr * ar - pi * ai;
        float ni = pr * ai + pi * ar;
        pr = nr; pi = ni;
    }
    lamT[s] = pr; lamT[NST + s] = pi;
}

// W1 row 2s = Bre[s,:], row 2s+1 = Bim[s,:]  (no gamma; applied fp32 in scan)
__global__ void pack_w1(const float* __restrict__ Bre, const float* __restrict__ Bim,
                        unsigned short* __restrict__ W1) {
    int idx = blockIdx.x * 256 + threadIdx.x;
    int n = idx >> 10, k = idx & 1023;
    int s = n >> 1;
    float v = (n & 1) ? Bim[s * DMODEL + k] : Bre[s * DMODEL + k];
    W1[idx] = f2bf(v);
}
// W2[n][2s] = Cre[n][s], W2[n][2s+1] = -Cim[n][s]
__global__ void pack_w2(const float* __restrict__ Cre, const float* __restrict__ Cim,
                        unsigned short* __restrict__ W2) {
    int idx = blockIdx.x * 256 + threadIdx.x;
    int n = idx >> 10, k = idx & 1023;
    int s = k >> 1;
    float v = (k & 1) ? -Cim[n * NST + s] : Cre[n * NST + s];
    W2[idx] = f2bf(v);
}

// ---------------- X fp32 -> bf16 (8 elems/thread) ----------------
__global__ __launch_bounds__(256)
void conv_x(const float4* __restrict__ X, uint4* __restrict__ Xb) {
    int i = blockIdx.x * 256 + threadIdx.x;
    float4 a = X[2 * i], b = X[2 * i + 1];
    Xb[i] = pack8(a, b);
}

// ===== bf16 MFMA GEMM: 128x128 tile, BK=64, 2-phase, gload_lds, XOR-swizzled LDS =====
// LDS [128][64] shorts per operand (rows = 128B). Swizzle (rule #21, both sides):
//   - gload dest linear (tid*16B); global source chunk pre-permuted c = s ^ (row&7)
//   - frag reads use (col16 ^ (row&7)) -> 16-lane groups span all 32 banks
// EPI=0: bf16 out; EPI=1: fp32 out + D*x epilogue.
template<int EPI>
__global__ __launch_bounds__(256, 4)
void gemm_bf16(const unsigned short* __restrict__ A, const unsigned short* __restrict__ B,
               void* __restrict__ out, const float* __restrict__ Dv,
               const float* __restrict__ Xf) {
    const int K = 1024, N = 1024;
    __shared__ __align__(16) unsigned short As[128 * 64];
    __shared__ __align__(16) unsigned short Bs[128 * 64];

    const int tid  = threadIdx.x;
    const int lane = tid & 63;
    const int wave = tid >> 6;
    const int wr   = wave >> 1, wc = wave & 1;
    const int fr   = lane & 15;
    const int g4   = lane >> 4;
    const int f7   = fr & 7;

    // XCD-aware swizzle (nwg = 1024, %8 == 0 -> bijective)
    const int lin   = blockIdx.y * gridDim.x + blockIdx.x;
    const int n_new = (lin & 7) * 128 + (lin >> 3);
    const int bx = n_new & 7, by = n_new >> 3;
    const int m0 = by * 128, n0 = bx * 128;

    // staging: thread covers (row = srow + 32*ld, 16B chunk = schunk) — coalesced
    const int srow   = tid >> 3;                    // 0..31
    const int schunk = (tid & 7) ^ (srow & 7);      // pre-swizzled source chunk
    const unsigned short* Asrc = A + (size_t)(m0 + srow) * K + schunk * 8;
    const unsigned short* Bsrc = B + (size_t)(n0 + srow) * K + schunk * 8;

    f32x4 acc[4][4] = {};

    for (int k0 = 0; k0 < K; k0 += 64) {
        __syncthreads();                  // prev tile's ds_reads done
        #pragma unroll
        for (int ld = 0; ld < 4; ++ld) {
            gload16(Asrc + (size_t)(ld * 32) * K + k0, &As[ld * 2048 + tid * 8]);
            gload16(Bsrc + (size_t)(ld * 32) * K + k0, &Bs[ld * 2048 + tid * 8]);
        }
        __syncthreads();                  // vmcnt drained -> LDS ready

        #pragma unroll
        for (int h = 0; h < 2; ++h) {
            s16x8 af[4], bfq[4];
            #pragma unroll
            for (int i = 0; i < 4; ++i) {
                const int row = wr * 64 + i * 16 + fr;
                af[i] = *(const s16x8*)&As[row * 64 + (((h * 4 + g4) ^ f7) << 3)];
            }
            #pragma unroll
            for (int j = 0; j < 4; ++j) {
                const int row = wc * 64 + j * 16 + fr;
                bfq[j] = *(const s16x8*)&Bs[row * 64 + (((h * 4 + g4) ^ f7) << 3)];
            }
            #pragma unroll
            for (int i = 0; i < 4; ++i)
                #pragma unroll
                for (int j = 0; j < 4; ++j)
                    mfma16(acc[i][j], af[i], bfq[j]);
        }
    }

    const int crow = g4 * 4;              // C/D: col=lane&15, row=g4*4+r
    const int ccol = fr;
    #pragma unroll
    for (int i = 0; i < 4; ++i) {
        #pragma unroll
        for (int j = 0; j < 4; ++j) {
            const int mbase = m0 + wr * 64 + i * 16 + crow;
            const int n     = n0 + wc * 64 + j * 16 + ccol;
            #pragma unroll
            for (int r = 0; r < 4; ++r) {
                const int m = mbase + r;
                if (EPI) {
                    ((float*)out)[(size_t)m * N + n] =
                        acc[i][j][r] + Dv[n] * Xf[(size_t)m * N + n];
                } else {
                    ((unsigned short*)out)[(size_t)m * N + n] = f2bf(acc[i][j][r]);
                }
            }
        }
    }
}

// ---------- scan pass 1: chunk ends only ----------
__global__ __launch_bounds__(128)
void scan_ends(const unsigned int* __restrict__ Bu, const float* __restrict__ lam,
               const float* __restrict__ gam, float* __restrict__ ends) {
    const int s = blockIdx.y * 128 + threadIdx.x;
    const int c = blockIdx.x;
    const float lr = lam[s], li = lam[NST + s], g = gam[s];
    float hr = 0.f, hi = 0.f;
    size_t base = (size_t)c * CHUNK * NST + s;
    #pragma unroll 4
    for (int t = 0; t < CHUNK; ++t) {
        unsigned int v = Bu[base + (size_t)t * NST];
        float br = g * bf2f(v & 0xffffu);
        float bi = g * bf2f(v >> 16);
        float nr = fmaf(lr, hr, fmaf(-li, hi, br));
        float ni = fmaf(lr, hi, fmaf( li, hr, bi));
        hr = nr; hi = ni;
    }
    ends[(size_t)(c * NST + s) * 2]     = hr;
    ends[(size_t)(c * NST + s) * 2 + 1] = hi;
}

// ---------- carry scan across chunks (16-deep static prefetch) ----------
__global__ __launch_bounds__(NST)
void scan_carry(const float* __restrict__ ends, const float* __restrict__ lamT,
                float* __restrict__ car) {
    const int s = threadIdx.x;
    const float ar = lamT[s], ai = lamT[NST + s];
    const float2* E = (const float2*)ends;   // index c*NST + s
    float2*       C = (float2*)car;
    float2 bufA[8], bufB[8];
    #pragma unroll
    for (int k = 0; k < 8; ++k) bufA[k] = E[(size_t)k * NST + s];
    float cr = 0.f, ci = 0.f;
    for (int cc = 0; cc < NCHUNK; cc += 16) {
        #pragma unroll
        for (int k = 0; k < 8; ++k)
            bufB[k] = E[(size_t)(cc + 8 + k) * NST + s];
        #pragma unroll
        for (int k = 0; k < 8; ++k) {
            float2 o; o.x = cr; o.y = ci;
            C[(size_t)(cc + k) * NST + s] = o;
            float nr = fmaf(ar, cr, fmaf(-ai, ci, bufA[k].x));
            float ni = fmaf(ar, ci, fmaf( ai, cr, bufA[k].y));
            cr = nr; ci = ni;
        }
        if (cc + 16 < NCHUNK) {
            #pragma unroll
            for (int k = 0; k < 8; ++k)
                bufA[k] = E[(size_t)(cc + 16 + k) * NST + s];
        }
        #pragma unroll
        for (int k = 0; k < 8; ++k) {
            float2 o; o.x = cr; o.y = ci;
            C[(size_t)(cc + 8 + k) * NST + s] = o;
            float nr = fmaf(ar, cr, fmaf(-ai, ci, bufB[k].x));
            float ni = fmaf(ar, ci, fmaf( ai, cr, bufB[k].y));
            cr = nr; ci = ni;
        }
    }
}

// ---------- scan pass 2: full scan from carry, write H bf16 (to Xb region) ----
__global__ __launch_bounds__(128)
void scan_h(const unsigned int* __restrict__ Bu, unsigned int* __restrict__ H,
            const float* __restrict__ lam, const float* __restrict__ gam,
            const float* __restrict__ car) {
    const int s = blockIdx.y * 128 + threadIdx.x;
    const int c = blockIdx.x;
    const float lr = lam[s], li = lam[NST + s], g = gam[s];
    float hr = car[(size_t)(c * NST + s) * 2];
    float hi = car[(size_t)(c * NST + s) * 2 + 1];
    size_t base = (size_t)c * CHUNK * NST + s;
    #pragma unroll 4
    for (int t = 0; t < CHUNK; ++t) {
        unsigned int v = Bu[base + (size_t)t * NST];
        float br = g * bf2f(v & 0xffffu);
        float bi = g * bf2f(v >> 16);
        float nr = fmaf(lr, hr, fmaf(-li, hi, br));
        float ni = fmaf(lr, hi, fmaf( li, hr, bi));
        hr = nr; hi = ni;
        H[base + (size_t)t * NST] =
            (unsigned int)f2bf(hr) | ((unsigned int)f2bf(hi) << 16);
    }
}

extern "C" void kernel_launch(void* const* d_in, const int* in_sizes, int n_in,
                              void* d_out, int out_size, void* d_ws, size_t ws_size,
                              hipStream_t stream) {
    const float* X         = (const float*)d_in[0];
    const float* nu_log    = (const float*)d_in[1];
    const float* theta_log = (const float*)d_in[2];
    const float* gamma_log = (const float*)d_in[3];
    const float* Bre       = (const float*)d_in[4];
    const float* Bim       = (const float*)d_in[5];
    const float* Cre       = (const float*)d_in[6];
    const float* Cim       = (const float*)d_in[7];
    const float* Dv        = (const float*)d_in[8];
    float* Y = (float*)d_out;

    // ws (~37 MB): Xb (later reused as H), W1, W2, small tables.
    // Bu (bf16 pairs, 32 MB) lives in d_out's first 32 MB; dead before gemm2 writes Y.
    char* ws = (char*)d_ws;
    size_t off = 0;
    unsigned short* Xb  = (unsigned short*)(ws + off); off += (size_t)L_SEQ * DMODEL * 2;  // 32MB
    unsigned short* H   = Xb;   // reuse: Xb dead after gemm1
    unsigned short* W1  = (unsigned short*)(ws + off); off += (size_t)DMODEL * DMODEL * 2; // 2MB
    unsigned short* W2  = (unsigned short*)(ws + off); off += (size_t)DMODEL * DMODEL * 2; // 2MB
    float* lam  = (float*)(ws + off); off += 1024 * 4;
    float* lamT = (float*)(ws + off); off += 1024 * 4;
    float* gam  = (float*)(ws + off); off += 512 * 4;
    float* ends = (float*)(ws + off); off += (size_t)NCHUNK * NST * 2 * 4;  // 512KB
    float* car  = (float*)(ws + off); off += (size_t)NCHUNK * NST * 2 * 4;  // 512KB
    unsigned short* Bu = (unsigned short*)d_out;

    setup_params<<<1, NST, 0, stream>>>(nu_log, theta_log, gamma_log, lam, lamT, gam);
    pack_w1<<<(DMODEL * DMODEL) / 256, 256, 0, stream>>>(Bre, Bim, W1);
    pack_w2<<<(DMODEL * DMODEL) / 256, 256, 0, stream>>>(Cre, Cim, W2);
    conv_x<<<(L_SEQ * DMODEL / 8) / 256, 256, 0, stream>>>((const float4*)X, (uint4*)Xb);

    dim3 gg(8, 128);
    gemm_bf16<0><<<gg, 256, 0, stream>>>(Xb, W1, Bu, nullptr, nullptr);

    dim3 gs(NCHUNK, 4);   // 128 chunks x 4 state-groups of 128
    scan_ends<<<gs, 128, 0, stream>>>((const unsigned int*)Bu, lam, gam, ends);
    scan_carry<<<1, NST, 0, stream>>>(ends, lamT, car);
    scan_h<<<gs, 128, 0, stream>>>((const unsigned int*)Bu, (unsigned int*)H, lam, gam, car);

    gemm_bf16<1><<<gg, 256, 0, stream>>>(H, W2, Y, Dv, X);
}